// Round 9
// baseline (809.943 us; speedup 1.0000x reference)
//
#include <hip/hip_runtime.h>
#include <hip/hip_bf16.h>

typedef unsigned short u16;
typedef unsigned int u32;
typedef __attribute__((ext_vector_type(8))) u16 u16x8;
typedef __attribute__((ext_vector_type(4))) u16 u16x4;
typedef __attribute__((ext_vector_type(8))) short bf16x8;
typedef __attribute__((ext_vector_type(4))) float f32x4;

__device__ __forceinline__ u16 f2bf(float f) {
  u32 u = __float_as_uint(f);
  u += 0x7fffu + ((u >> 16) & 1u);
  return (u16)(u >> 16);
}
__device__ __forceinline__ float bf2f(u16 h) {
  return __uint_as_float(((u32)h) << 16);
}
__device__ __forceinline__ u16 cvt_bf(float f) {
  __hip_bfloat16 h(f);
  return __builtin_bit_cast(u16, h);
}
__device__ __forceinline__ bf16x8 ld_bf8(const u16* p) {
  return __builtin_bit_cast(bf16x8, *(const u16x8*)p);
}

#if __has_builtin(__builtin_amdgcn_exp2f)
#define EXP2(x) __builtin_amdgcn_exp2f(x)
#else
#define EXP2(x) exp2f(x)
#endif

typedef const void __attribute__((address_space(1)))* gas_t;
typedef void __attribute__((address_space(3)))* las_t;
#define GLOAD_LDS16(gp, lp) __builtin_amdgcn_global_load_lds((gas_t)(gp), (las_t)(lp), 16, 0, 0)

#define QSCALE 0.25503486f
#define BIAS_MUL 23.08312065f  // 16 * log2(e)

// ---------------- weight transpose f32 [K][N] -> bf16 [N][K] ----------------
__global__ void wtrans_kernel(const float* __restrict__ in, u16* __restrict__ out, int K, int N) {
  int idx = blockIdx.x * 256 + threadIdx.x;
  if (idx >= K * N) return;
  int n = idx / K, k = idx - n * K;
  out[idx] = f2bf(in[(size_t)k * N + n]);
}

// fc1 transpose with val/gate 16-col interleave
__global__ void wtrans_fc1_kernel(const float* __restrict__ in, u16* __restrict__ out) {
  int idx = blockIdx.x * 256 + threadIdx.x;  // over 2048*512
  int n = idx >> 9, k = idx & 511;
  int i = ((n >> 5) << 4) | (n & 15);
  int gsel = (n >> 4) & 1;
  out[idx] = f2bf(in[(size_t)k * 2048 + i + gsel * 1024]);
}

// ---------------- CPB MLP: tab2[h][t] = 16*log2e*sigmoid(...) - 23 (pre-shifted) ----------------
__global__ void cpb_kernel(const float* __restrict__ rt, const float* __restrict__ w1,
                           const float* __restrict__ b1, const float* __restrict__ w2,
                           float* __restrict__ tab2) {
  __shared__ float hid[512];
  __shared__ float part[16][17];
  int tix = blockIdx.x;  // 0..960
  int t = threadIdx.x;
  float r0 = rt[tix * 2], r1 = rt[tix * 2 + 1];
  for (int j = t; j < 512; j += 256) {
    float v = r0 * w1[j] + r1 * w1[512 + j] + b1[j];
    hid[j] = v > 0.f ? v : 0.f;
  }
  __syncthreads();
  int hh = t & 15, seg = t >> 4;
  float acc = 0.f;
  for (int j = seg * 32; j < seg * 32 + 32; ++j) acc += hid[j] * w2[j * 16 + hh];
  part[seg][hh] = acc;
  __syncthreads();
  if (t < 16) {
    float s = 0.f;
    for (int g = 0; g < 16; ++g) s += part[g][t];
    tab2[t * 961 + tix] = BIAS_MUL / (1.f + __expf(-s)) - 23.0f;
  }
}

// ---------------- LN1: x(B,C,H,W) -> hbuf/xwbuf token-major bf16 (32 pixels/block) ----------------
__global__ __launch_bounds__(256, 4) void ln1_kernel(
    const float* __restrict__ x, const float* __restrict__ w, const float* __restrict__ b,
    u16* __restrict__ hbuf, u16* __restrict__ xwbuf) {
  __shared__ u16 tile[512 * 33];
  __shared__ float red[2][8][32];
  __shared__ float meanv[32], rstdv[32];
  int bi = blockIdx.x;
  int bimg = bi >> 7, rest = bi & 127, hrow = rest >> 1, half = rest & 1;
  int t = threadIdx.x, p = t & 31, g = t >> 5;
  const float* xr = x + (size_t)bimg * 512 * 4096 + (size_t)hrow * 64 + half * 32;
  float s = 0.f, s2 = 0.f;
  for (int i = 0; i < 64; ++i) {
    int c = g * 64 + i;
    float v = xr[(size_t)c * 4096 + p];
    tile[c * 33 + p] = f2bf(v);
    s += v; s2 += v * v;
  }
  red[0][g][p] = s; red[1][g][p] = s2;
  __syncthreads();
  if (t < 32) {
    float ss = 0.f, qq = 0.f;
    for (int gg = 0; gg < 8; ++gg) { ss += red[0][gg][t]; qq += red[1][gg][t]; }
    float mu = ss * (1.f / 512.f);
    float var = qq * (1.f / 512.f) - mu * mu;
    meanv[t] = mu;
    rstdv[t] = rsqrtf(var + 1e-5f);
  }
  __syncthreads();
  int c0 = t * 2;
  float w0 = w[c0], w1v = w[c0 + 1], b0 = b[c0], b1v = b[c0 + 1];
  int hy = hrow >> 4, iy = hrow & 15;
  for (int pp = 0; pp < 32; ++pp) {
    int pixel = half * 32 + pp;
    int wx = pixel >> 4, ix = pixel & 15;
    int widx = bimg * 16 + hy * 4 + wx;
    size_t basep = ((size_t)widx * 256 + iy * 16 + ix) * 512;
    u16 rb0 = tile[c0 * 33 + pp], rb1 = tile[(c0 + 1) * 33 + pp];
    float mu = meanv[pp], rs = rstdv[pp];
    float v0 = bf2f(rb0), v1 = bf2f(rb1);
    *(u32*)(xwbuf + basep + c0) = (u32)rb0 | ((u32)rb1 << 16);
    u16 h0 = f2bf((v0 - mu) * rs * w0 + b0);
    u16 h1 = f2bf((v1 - mu) * rs * w1v + b1v);
    *(u32*)(hbuf + basep + c0) = (u32)h0 | ((u32)h1 << 16);
  }
}

// ---------------- 128x128 bf16 MFMA GEMM (R5 proven), XCD-panel mapping ----------------
// EPI: 1 out = acc + res, 4 fused final: out_f32(CHW) = acc + res + x
template <int EPI>
__global__ __launch_bounds__(256, 4) void gemm_bt(
    const u16* __restrict__ A, const u16* __restrict__ Bt,
    u16* __restrict__ out, const u16* __restrict__ res,
    const float* __restrict__ xg, float* __restrict__ outf,
    int M, int N, int K) {
  __shared__ u16 As[128 * 64];
  __shared__ u16 Bs[128 * 64];
  const int t = threadIdx.x, l = t & 63, wv = t >> 6;
  const int nbx = N >> 7;
  const int wg = (int)blockIdx.x;
  const int xcd = wg & 7, c = wg >> 3;
  const int cm = c / nbx;
  const int m0 = (xcd * 64 + cm) * 128, n0 = (c - cm * nbx) * 128;
  const int wr = wv >> 1, wc = wv & 1;
  const int lr = l & 15, lk = l >> 4;
  f32x4 acc[4][4] = {};
  for (int kt = 0; kt < K; kt += 64) {
#pragma unroll
    for (int j = 0; j < 4; ++j) {
      int qi = j * 256 + t;
      int r = qi >> 3, c8 = (qi & 7) * 8;
      GLOAD_LDS16(A + (size_t)(m0 + r) * K + kt + c8, As + (size_t)(j * 256 + wv * 64) * 8);
    }
#pragma unroll
    for (int j = 0; j < 4; ++j) {
      int qi = j * 256 + t;
      int r = qi >> 3, c8 = (qi & 7) * 8;
      GLOAD_LDS16(Bt + (size_t)(n0 + r) * K + kt + c8, Bs + (size_t)(j * 256 + wv * 64) * 8);
    }
    __syncthreads();
#pragma unroll
    for (int ks = 0; ks < 2; ++ks) {
      bf16x8 a[4], bb[4];
#pragma unroll
      for (int mf = 0; mf < 4; ++mf)
        a[mf] = ld_bf8(As + (wr * 64 + mf * 16 + lr) * 64 + ks * 32 + lk * 8);
#pragma unroll
      for (int nf = 0; nf < 4; ++nf)
        bb[nf] = ld_bf8(Bs + (wc * 64 + nf * 16 + lr) * 64 + ks * 32 + lk * 8);
#pragma unroll
      for (int mf = 0; mf < 4; ++mf)
#pragma unroll
        for (int nf = 0; nf < 4; ++nf)
          acc[mf][nf] = __builtin_amdgcn_mfma_f32_16x16x32_bf16(a[mf], bb[nf], acc[mf][nf], 0, 0, 0);
    }
    __syncthreads();
  }
#pragma unroll
  for (int mf = 0; mf < 4; ++mf) {
    int rbase = m0 + wr * 64 + mf * 16 + lk * 4;
    if constexpr (EPI == 4) {
      int widx = rbase >> 8, iy = (rbase >> 4) & 15, ix0 = rbase & 15;
      int bimg = widx >> 4, hy = (widx >> 2) & 3, wx = widx & 3;
#pragma unroll
      for (int nf = 0; nf < 4; ++nf) {
        int col = n0 + wc * 64 + nf * 16 + lr;
        size_t obase = (((size_t)(bimg * 512 + col) * 64) + hy * 16 + iy) * 64 + wx * 16 + ix0;
        const float* xp = xg + obase;
        float* op = outf + obase;
#pragma unroll
        for (int jj = 0; jj < 4; ++jj)
          op[jj] = acc[mf][nf][jj] + bf2f(res[(size_t)(rbase + jj) * 512 + col]) + xp[jj];
      }
    } else {
#pragma unroll
      for (int nf = 0; nf < 4; ++nf) {
        int col = n0 + wc * 64 + nf * 16 + lr;
#pragma unroll
        for (int jj = 0; jj < 4; ++jj) {
          int row = rbase + jj;
          out[(size_t)row * N + col] = f2bf(acc[mf][nf][jj] + bf2f(res[(size_t)row * N + col]));
        }
      }
    }
  }
}

// ---------------- 256x256 8-wave deep-pipelined GEMM (8-phase template port) ----------------
// T2 seg-XOR swizzle (source-preswizzled global_load_lds + swizzled ds_read),
// T4 counted vmcnt(8) (never 0 mid-loop), T3 4-phase/K-tile split, T5 setprio.
// M fixed 65536 (256 row-panels, 32/XCD). EPI: 2 qkv scatter, 3 fused SwiGLU.
template <int EPI>
__global__ __launch_bounds__(512, 2) void gemm8(
    const u16* __restrict__ A, const u16* __restrict__ Bt,
    u16* __restrict__ out,
    u16* __restrict__ q_o, u16* __restrict__ k_o, u16* __restrict__ v_o,
    int N, int K) {
  __shared__ u16 As[2][256 * 64];
  __shared__ u16 Bs[2][256 * 64];
  const int t = threadIdx.x;
  const int l = t & 63;
  const int wid = t >> 6;
  const int wr = wid >> 2, wc = wid & 3;   // 2M x 4N wave grid
  const int lr = l & 15, lk = l >> 4;
  const int nbx = N >> 8;
  const int wg = (int)blockIdx.x;
  const int xcd = wg & 7, c = wg >> 3;
  const int cm = c / nbx;
  const int m0 = (xcd * 32 + cm) * 256;
  const int n0 = (c - cm * nbx) * 256;
  const int swz = lr & 7;

  auto stage = [&](int b, int kt) {
#pragma unroll
    for (int j = 0; j < 4; ++j) {
      int seg = j * 512 + t;
      int row = seg >> 3, s = seg & 7;
      int col8 = (s ^ (row & 7)) << 3;  // pre-swizzled source
      GLOAD_LDS16(A + (size_t)(m0 + row) * K + kt + col8, &As[b][seg * 8]);
    }
#pragma unroll
    for (int j = 0; j < 4; ++j) {
      int seg = j * 512 + t;
      int row = seg >> 3, s = seg & 7;
      int col8 = (s ^ (row & 7)) << 3;
      GLOAD_LDS16(Bt + (size_t)(n0 + row) * K + kt + col8, &Bs[b][seg * 8]);
    }
  };

  f32x4 acc[8][4] = {};
  const int nt = K >> 6;
  stage(0, 0);
  for (int tt = 0; tt < nt; ++tt) {
    if (tt + 1 < nt) {
      stage((tt + 1) & 1, (tt + 1) * 64);
      asm volatile("s_waitcnt vmcnt(8)" ::: "memory");  // old K-tile landed; 8 stay in flight
    } else {
      asm volatile("s_waitcnt vmcnt(0)" ::: "memory");
    }
    __builtin_amdgcn_s_barrier();
    const u16* as = &As[tt & 1][0];
    const u16* bs = &Bs[tt & 1][0];
    bf16x8 af[4], bf[4];
    // ---- phase 0: ks=0, mf 0-3 (reads A subtile + B ks0) ----
#pragma unroll
    for (int mf = 0; mf < 4; ++mf)
      af[mf] = ld_bf8(as + (wr * 128 + mf * 16 + lr) * 64 + ((lk ^ swz) << 3));
#pragma unroll
    for (int nf = 0; nf < 4; ++nf)
      bf[nf] = ld_bf8(bs + (wc * 64 + nf * 16 + lr) * 64 + ((lk ^ swz) << 3));
    __builtin_amdgcn_s_barrier();
    __builtin_amdgcn_s_setprio(1);
#pragma unroll
    for (int mf = 0; mf < 4; ++mf)
#pragma unroll
      for (int nf = 0; nf < 4; ++nf)
        acc[mf][nf] = __builtin_amdgcn_mfma_f32_16x16x32_bf16(af[mf], bf[nf], acc[mf][nf], 0, 0, 0);
    __builtin_amdgcn_s_setprio(0);
    __builtin_amdgcn_s_barrier();
    // ---- phase 1: ks=0, mf 4-7 (B reused) ----
    bf16x8 ag[4];
#pragma unroll
    for (int mf = 0; mf < 4; ++mf)
      ag[mf] = ld_bf8(as + (wr * 128 + (mf + 4) * 16 + lr) * 64 + ((lk ^ swz) << 3));
    __builtin_amdgcn_s_barrier();
    __builtin_amdgcn_s_setprio(1);
#pragma unroll
    for (int mf = 0; mf < 4; ++mf)
#pragma unroll
      for (int nf = 0; nf < 4; ++nf)
        acc[mf + 4][nf] = __builtin_amdgcn_mfma_f32_16x16x32_bf16(ag[mf], bf[nf], acc[mf + 4][nf], 0, 0, 0);
    __builtin_amdgcn_s_setprio(0);
    __builtin_amdgcn_s_barrier();
    // ---- phase 2: ks=1, mf 0-3 (+ B ks1) ----
#pragma unroll
    for (int mf = 0; mf < 4; ++mf)
      af[mf] = ld_bf8(as + (wr * 128 + mf * 16 + lr) * 64 + (((4 | lk) ^ swz) << 3));
#pragma unroll
    for (int nf = 0; nf < 4; ++nf)
      bf[nf] = ld_bf8(bs + (wc * 64 + nf * 16 + lr) * 64 + (((4 | lk) ^ swz) << 3));
    __builtin_amdgcn_s_barrier();
    __builtin_amdgcn_s_setprio(1);
#pragma unroll
    for (int mf = 0; mf < 4; ++mf)
#pragma unroll
      for (int nf = 0; nf < 4; ++nf)
        acc[mf][nf] = __builtin_amdgcn_mfma_f32_16x16x32_bf16(af[mf], bf[nf], acc[mf][nf], 0, 0, 0);
    __builtin_amdgcn_s_setprio(0);
    __builtin_amdgcn_s_barrier();
    // ---- phase 3: ks=1, mf 4-7 ----
#pragma unroll
    for (int mf = 0; mf < 4; ++mf)
      ag[mf] = ld_bf8(as + (wr * 128 + (mf + 4) * 16 + lr) * 64 + (((4 | lk) ^ swz) << 3));
    __builtin_amdgcn_s_barrier();
    __builtin_amdgcn_s_setprio(1);
#pragma unroll
    for (int mf = 0; mf < 4; ++mf)
#pragma unroll
      for (int nf = 0; nf < 4; ++nf)
        acc[mf + 4][nf] = __builtin_amdgcn_mfma_f32_16x16x32_bf16(ag[mf], bf[nf], acc[mf + 4][nf], 0, 0, 0);
    __builtin_amdgcn_s_setprio(0);
    __builtin_amdgcn_s_barrier();
  }
  // ---- epilogue ----
#pragma unroll
  for (int mf = 0; mf < 8; ++mf) {
    int rbase = m0 + wr * 128 + mf * 16 + lk * 4;
    if constexpr (EPI == 3) {
#pragma unroll
      for (int nf = 0; nf < 4; nf += 2) {
        int colv = n0 + wc * 64 + nf * 16 + lr;
        int i = ((colv >> 5) << 4) | (colv & 15);
#pragma unroll
        for (int jj = 0; jj < 4; ++jj) {
          int row = rbase + jj;
          float val = acc[mf][nf][jj], gate = acc[mf][nf + 1][jj];
          float sil = gate / (1.f + __expf(-gate));
          out[(size_t)row * 1024 + i] = f2bf(sil * val);
        }
      }
    } else {  // EPI == 2 qkv scatter
#pragma unroll
      for (int nf = 0; nf < 4; ++nf) {
        int col = n0 + wc * 64 + nf * 16 + lr;
        int which = col >> 9, rem = col & 511;
        int hh = rem >> 5, dd = rem & 31;
        u16* po = which == 0 ? q_o : (which == 1 ? k_o : v_o);
        float sc = which == 0 ? QSCALE : 1.f;
#pragma unroll
        for (int jj = 0; jj < 4; ++jj) {
          int row = rbase + jj;
          size_t dst = (((size_t)(row >> 8) * 16 + hh) * 256 + (size_t)(row & 255)) * 32 + dd;
          po[dst] = f2bf(acc[mf][nf][jj] * sc);
        }
      }
    }
  }
}

// ---------------- windowed flash attention (R8 proven) ----------------
__global__ __launch_bounds__(256, 4) void attn_kernel(
    const u16* __restrict__ qb, const u16* __restrict__ kb, const u16* __restrict__ vb,
    const float* __restrict__ tab2, u16* __restrict__ ob) {
  __shared__ u16 vt[32 * 72];
  __shared__ float tabh4[31 * 32 * 4];
  __shared__ u16 pl[4][16 * 76];
  const int w = blockIdx.x, h = blockIdx.y;
  const int t = threadIdx.x, l = t & 63, wid = t >> 6;
  const size_t base = (size_t)(w * 16 + h) * 256 * 32;
  const u16* qg = qb + base;
  const u16* kg = kb + base;
  const u16* vg = vb + base;
  const float* th = tab2 + h * 961;
  for (int i = t; i < 992; i += 256) {
    int dy = i >> 5, dx = i & 31;
#pragma unroll
    for (int r = 0; r < 4; ++r) {
      int dxr = dx + r;
      tabh4[i * 4 + r] = (dxr <= 30) ? th[dy * 31 + dxr] : 0.f;
    }
  }
  const int q4 = l >> 4, c0 = l & 15;
  const int dx0 = q4 * 4 - c0 + 15;
  bf16x8 qa[4];
#pragma unroll
  for (int mf = 0; mf < 4; ++mf)
    qa[mf] = ld_bf8(qg + (wid * 64 + mf * 16 + c0) * 32 + q4 * 8);
  f32x4 oacc[4][2] = {};
  float psum[4][4] = {};
  for (int ct = 0; ct < 4; ++ct) {
    {
      int r = t & 63, j = t >> 6;
      u16x8 dv = *(const u16x8*)(vg + (ct * 64 + r) * 32 + j * 8);
#pragma unroll
      for (int e = 0; e < 8; ++e) vt[(j * 8 + e) * 72 + r] = dv[e];
    }
    __syncthreads();
    bf16x8 bfr[4];
#pragma unroll
    for (int nf = 0; nf < 4; ++nf)
      bfr[nf] = ld_bf8(kg + (ct * 64 + nf * 16 + c0) * 32 + q4 * 8);
    bf16x8 vfr[2][2];
#pragma unroll
    for (int df = 0; df < 2; ++df)
#pragma unroll
      for (int ks2 = 0; ks2 < 2; ++ks2)
        vfr[df][ks2] = ld_bf8(vt + (df * 16 + c0) * 72 + ks2 * 32 + q4 * 8);
#pragma unroll
    for (int mf = 0; mf < 4; ++mf) {
      const int dyb = wid * 4 + mf - ct * 4 + 15;
      f32x4 sacc[4];
#pragma unroll
      for (int nf = 0; nf < 4; ++nf)
        sacc[nf] = *(const f32x4*)&tabh4[((dyb - nf) * 32 + dx0) * 4];
      __builtin_amdgcn_s_setprio(1);
#pragma unroll
      for (int nf = 0; nf < 4; ++nf)
        sacc[nf] = __builtin_amdgcn_mfma_f32_16x16x32_bf16(qa[mf], bfr[nf], sacc[nf], 0, 0, 0);
      __builtin_amdgcn_s_setprio(0);
#pragma unroll
      for (int nf = 0; nf < 4; ++nf) {
#pragma unroll
        for (int jj = 0; jj < 4; ++jj) {
          float p = EXP2(sacc[nf][jj]);
          psum[mf][jj] += p;
          pl[wid][(q4 * 4 + jj) * 76 + nf * 16 + c0] = cvt_bf(p);
        }
      }
      __builtin_amdgcn_s_setprio(1);
#pragma unroll
      for (int ks2 = 0; ks2 < 2; ++ks2) {
        bf16x8 pa = ld_bf8(&pl[wid][c0 * 76 + ks2 * 32 + q4 * 8]);
        oacc[mf][0] = __builtin_amdgcn_mfma_f32_16x16x32_bf16(pa, vfr[0][ks2], oacc[mf][0], 0, 0, 0);
        oacc[mf][1] = __builtin_amdgcn_mfma_f32_16x16x32_bf16(pa, vfr[1][ks2], oacc[mf][1], 0, 0, 0);
      }
      __builtin_amdgcn_s_setprio(0);
    }
    __syncthreads();
  }
#pragma unroll
  for (int mf = 0; mf < 4; ++mf) {
#pragma unroll
    for (int jj = 0; jj < 4; ++jj) {
      float s = psum[mf][jj];
      s += __shfl_xor(s, 1);
      s += __shfl_xor(s, 2);
      s += __shfl_xor(s, 4);
      s += __shfl_xor(s, 8);
      float inv = 1.f / s;
      int row = wid * 64 + mf * 16 + q4 * 4 + jj;
      size_t obase = ((size_t)w * 256 + row) * 512 + h * 32;
      ob[obase + c0] = f2bf(oacc[mf][0][jj] * inv);
      ob[obase + 16 + c0] = f2bf(oacc[mf][1][jj] * inv);
    }
  }
}

// ---------------- LN2 ----------------
__global__ __launch_bounds__(256, 4) void ln2_kernel(const u16* __restrict__ r1,
    const float* __restrict__ w, const float* __restrict__ b, u16* __restrict__ h2) {
  int t = threadIdx.x, l = t & 63, wid = t >> 6;
  size_t token = (size_t)blockIdx.x * 4 + wid;
  const u16* rp = r1 + token * 512 + l * 8;
  u16x8 raw = *(const u16x8*)rp;
  float v[8]; float s = 0.f, s2 = 0.f;
#pragma unroll
  for (int i = 0; i < 8; ++i) { v[i] = bf2f(raw[i]); s += v[i]; s2 += v[i] * v[i]; }
#pragma unroll
  for (int m = 1; m < 64; m <<= 1) { s += __shfl_xor(s, m); s2 += __shfl_xor(s2, m); }
  float mu = s * (1.f / 512.f);
  float var = s2 * (1.f / 512.f) - mu * mu;
  float rs = rsqrtf(var + 1e-5f);
  u16x8 o;
#pragma unroll
  for (int i = 0; i < 8; ++i) {
    int c = l * 8 + i;
    o[i] = f2bf((v[i] - mu) * rs * w[c] + b[c]);
  }
  *(u16x8*)(h2 + token * 512 + l * 8) = o;
}

extern "C" void kernel_launch(void* const* d_in, const int* in_sizes, int n_in,
                              void* d_out, int out_size, void* d_ws, size_t ws_size,
                              hipStream_t stream) {
  (void)in_sizes; (void)n_in; (void)out_size; (void)ws_size;
  const float* x = (const float*)d_in[0];
  const float* rel_table = (const float*)d_in[1];
  const float* n1w = (const float*)d_in[2];
  const float* n1b = (const float*)d_in[3];
  const float* n2w = (const float*)d_in[4];
  const float* n2b = (const float*)d_in[5];
  const float* qkv_w = (const float*)d_in[6];
  const float* proj_w = (const float*)d_in[7];
  const float* cpb_w1 = (const float*)d_in[8];
  const float* cpb_b1 = (const float*)d_in[9];
  const float* cpb_w2 = (const float*)d_in[10];
  const float* fc1_w = (const float*)d_in[11];
  const float* fc2_w = (const float*)d_in[12];
  float* outp = (float*)d_out;
  char* ws = (char*)d_ws;

  u16* wq = (u16*)(ws + 0);              // 1536x512 bf16
  u16* wp = (u16*)(ws + 1572864);        // 512x512
  u16* w1 = (u16*)(ws + 2097152);        // 2048x512 (permuted)
  u16* w2 = (u16*)(ws + 4194304);        // 512x1024
  float* tab2 = (float*)(ws + 5242880);  // 16x961 f32 (pre-shifted)
  const size_t RB = 67108864;
  u16* R0 = (u16*)(ws + 8388608);            // xwbuf (proj residual)
  u16* R1 = (u16*)(ws + 8388608 + RB);       // r1
  u16* R2 = (u16*)(ws + 8388608 + 2 * RB);   // hbuf -> obuf
  u16* R3 = (u16*)(ws + 8388608 + 3 * RB);   // qbuf -> h2
  u16* R4 = (u16*)(ws + 8388608 + 4 * RB);   // kbuf -> gbuf (spans R4+R5)
  u16* R5 = (u16*)(ws + 8388608 + 5 * RB);   // vbuf

  wtrans_kernel<<<3072, 256, 0, stream>>>(qkv_w, wq, 512, 1536);
  wtrans_kernel<<<1024, 256, 0, stream>>>(proj_w, wp, 512, 512);
  wtrans_fc1_kernel<<<4096, 256, 0, stream>>>(fc1_w, w1);
  wtrans_kernel<<<2048, 256, 0, stream>>>(fc2_w, w2, 1024, 512);
  cpb_kernel<<<961, 256, 0, stream>>>(rel_table, cpb_w1, cpb_b1, cpb_w2, tab2);
  ln1_kernel<<<2048, 256, 0, stream>>>(x, n1w, n1b, R2, R0);
  gemm8<2><<<1536, 512, 0, stream>>>(R2, wq, nullptr, R3, R4, R5, 1536, 512);
  attn_kernel<<<dim3(256, 16), 256, 0, stream>>>(R3, R4, R5, tab2, R2);
  gemm_bt<1><<<2048, 256, 0, stream>>>(R2, wp, R1, R0,
                                       nullptr, nullptr, 65536, 512, 512);
  ln2_kernel<<<16384, 256, 0, stream>>>(R1, n2w, n2b, R3);
  gemm8<3><<<2048, 512, 0, stream>>>(R3, w1, R4, nullptr, nullptr, nullptr, 2048, 512);
  gemm_bt<4><<<2048, 256, 0, stream>>>(R4, w2, nullptr, R1,
                                       x, outp, 65536, 512, 1024);
}

// Round 10
// 746.722 us; speedup vs baseline: 1.0847x; 1.0847x over previous
//
#include <hip/hip_runtime.h>
#include <hip/hip_bf16.h>

typedef unsigned short u16;
typedef unsigned int u32;
typedef __attribute__((ext_vector_type(8))) u16 u16x8;
typedef __attribute__((ext_vector_type(4))) u16 u16x4;
typedef __attribute__((ext_vector_type(8))) short bf16x8;
typedef __attribute__((ext_vector_type(4))) float f32x4;

__device__ __forceinline__ u16 f2bf(float f) {
  u32 u = __float_as_uint(f);
  u += 0x7fffu + ((u >> 16) & 1u);
  return (u16)(u >> 16);
}
__device__ __forceinline__ float bf2f(u16 h) {
  return __uint_as_float(((u32)h) << 16);
}
__device__ __forceinline__ u16 cvt_bf(float f) {
  __hip_bfloat16 h(f);
  return __builtin_bit_cast(u16, h);
}
__device__ __forceinline__ bf16x8 ld_bf8(const u16* p) {
  return __builtin_bit_cast(bf16x8, *(const u16x8*)p);
}

#if __has_builtin(__builtin_amdgcn_exp2f)
#define EXP2(x) __builtin_amdgcn_exp2f(x)
#else
#define EXP2(x) exp2f(x)
#endif

typedef const void __attribute__((address_space(1)))* gas_t;
typedef void __attribute__((address_space(3)))* las_t;
#define GLOAD_LDS16(gp, lp) __builtin_amdgcn_global_load_lds((gas_t)(gp), (las_t)(lp), 16, 0, 0)

#define QSCALE 0.25503486f       // (1/sqrt(32)) * log2(e), folded into wq q-columns
#define BIAS_MUL 23.08312065f    // 16 * log2(e)

// ---------------- weight transpose f32 [K][N] -> bf16 [N][K] ----------------
__global__ void wtrans_kernel(const float* __restrict__ in, u16* __restrict__ out, int K, int N) {
  int idx = blockIdx.x * 256 + threadIdx.x;
  if (idx >= K * N) return;
  int n = idx / K, k = idx - n * K;
  out[idx] = f2bf(in[(size_t)k * N + n]);
}

// qkv transpose with QSCALE folded into the q columns (n < 512)
__global__ void wtrans_qkv_kernel(const float* __restrict__ in, u16* __restrict__ out) {
  int idx = blockIdx.x * 256 + threadIdx.x;  // over 1536*512
  int n = idx >> 9, k = idx & 511;
  float s = n < 512 ? QSCALE : 1.f;
  out[idx] = f2bf(in[(size_t)k * 1536 + n] * s);
}

// fc1 transpose with val/gate 16-col interleave
__global__ void wtrans_fc1_kernel(const float* __restrict__ in, u16* __restrict__ out) {
  int idx = blockIdx.x * 256 + threadIdx.x;  // over 2048*512
  int n = idx >> 9, k = idx & 511;
  int i = ((n >> 5) << 4) | (n & 15);
  int gsel = (n >> 4) & 1;
  out[idx] = f2bf(in[(size_t)k * 2048 + i + gsel * 1024]);
}

// ---------------- CPB MLP: tab2[h][t] = 16*log2e*sigmoid(...) - 23 (pre-shifted) ----------------
__global__ void cpb_kernel(const float* __restrict__ rt, const float* __restrict__ w1,
                           const float* __restrict__ b1, const float* __restrict__ w2,
                           float* __restrict__ tab2) {
  __shared__ float hid[512];
  __shared__ float part[16][17];
  int tix = blockIdx.x;  // 0..960
  int t = threadIdx.x;
  float r0 = rt[tix * 2], r1 = rt[tix * 2 + 1];
  for (int j = t; j < 512; j += 256) {
    float v = r0 * w1[j] + r1 * w1[512 + j] + b1[j];
    hid[j] = v > 0.f ? v : 0.f;
  }
  __syncthreads();
  int hh = t & 15, seg = t >> 4;
  float acc = 0.f;
  for (int j = seg * 32; j < seg * 32 + 32; ++j) acc += hid[j] * w2[j * 16 + hh];
  part[seg][hh] = acc;
  __syncthreads();
  if (t < 16) {
    float s = 0.f;
    for (int g = 0; g < 16; ++g) s += part[g][t];
    tab2[t * 961 + tix] = BIAS_MUL / (1.f + __expf(-s)) - 23.0f;
  }
}

// ---------------- LN1: x(B,C,H,W) -> hbuf token-major bf16 (32 pixels/block) ----------------
__global__ __launch_bounds__(256, 4) void ln1_kernel(
    const float* __restrict__ x, const float* __restrict__ w, const float* __restrict__ b,
    u16* __restrict__ hbuf) {
  __shared__ u16 tile[512 * 33];
  __shared__ float red[2][8][32];
  __shared__ float meanv[32], rstdv[32];
  int bi = blockIdx.x;
  int bimg = bi >> 7, rest = bi & 127, hrow = rest >> 1, half = rest & 1;
  int t = threadIdx.x, p = t & 31, g = t >> 5;
  const float* xr = x + (size_t)bimg * 512 * 4096 + (size_t)hrow * 64 + half * 32;
  float s = 0.f, s2 = 0.f;
  for (int i = 0; i < 64; ++i) {
    int c = g * 64 + i;
    float v = xr[(size_t)c * 4096 + p];
    tile[c * 33 + p] = f2bf(v);
    s += v; s2 += v * v;
  }
  red[0][g][p] = s; red[1][g][p] = s2;
  __syncthreads();
  if (t < 32) {
    float ss = 0.f, qq = 0.f;
    for (int gg = 0; gg < 8; ++gg) { ss += red[0][gg][t]; qq += red[1][gg][t]; }
    float mu = ss * (1.f / 512.f);
    float var = qq * (1.f / 512.f) - mu * mu;
    meanv[t] = mu;
    rstdv[t] = rsqrtf(var + 1e-5f);
  }
  __syncthreads();
  int c0 = t * 2;
  float w0 = w[c0], w1v = w[c0 + 1], b0 = b[c0], b1v = b[c0 + 1];
  int hy = hrow >> 4, iy = hrow & 15;
  for (int pp = 0; pp < 32; ++pp) {
    int pixel = half * 32 + pp;
    int wx = pixel >> 4, ix = pixel & 15;
    int widx = bimg * 16 + hy * 4 + wx;
    size_t basep = ((size_t)widx * 256 + iy * 16 + ix) * 512;
    u16 rb0 = tile[c0 * 33 + pp], rb1 = tile[(c0 + 1) * 33 + pp];
    float mu = meanv[pp], rs = rstdv[pp];
    float v0 = bf2f(rb0), v1 = bf2f(rb1);
    u16 h0 = f2bf((v0 - mu) * rs * w0 + b0);
    u16 h1 = f2bf((v1 - mu) * rs * w1v + b1v);
    *(u32*)(hbuf + basep + c0) = (u32)h0 | ((u32)h1 << 16);
  }
}

// ---------------- 128x128 bf16 MFMA GEMM (R5/R8 proven), XCD-panel mapping ----------------
// EPI: 0 plain bf16 [row][N], 3 fused SwiGLU (permuted w1),
//      4 fused final: out_f32(CHW) = acc + res(bf16 token-major) + x(f32 CHW),
//      5 proj: out_bf16 token-major = acc + x(f32 CHW, window-partition mapping)
template <int EPI>
__global__ __launch_bounds__(256, 4) void gemm_bt(
    const u16* __restrict__ A, const u16* __restrict__ Bt,
    u16* __restrict__ out, const u16* __restrict__ res,
    const float* __restrict__ xg, float* __restrict__ outf,
    int M, int N, int K) {
  __shared__ u16 As[128 * 64];
  __shared__ u16 Bs[128 * 64];
  const int t = threadIdx.x, l = t & 63, wv = t >> 6;
  const int nbx = N >> 7;
  const int wg = (int)blockIdx.x;
  const int xcd = wg & 7, c = wg >> 3;
  const int cm = c / nbx;
  const int m0 = (xcd * 64 + cm) * 128, n0 = (c - cm * nbx) * 128;
  const int wr = wv >> 1, wc = wv & 1;
  const int lr = l & 15, lk = l >> 4;
  f32x4 acc[4][4] = {};
  for (int kt = 0; kt < K; kt += 64) {
#pragma unroll
    for (int j = 0; j < 4; ++j) {
      int qi = j * 256 + t;
      int r = qi >> 3, c8 = (qi & 7) * 8;
      GLOAD_LDS16(A + (size_t)(m0 + r) * K + kt + c8, As + (size_t)(j * 256 + wv * 64) * 8);
    }
#pragma unroll
    for (int j = 0; j < 4; ++j) {
      int qi = j * 256 + t;
      int r = qi >> 3, c8 = (qi & 7) * 8;
      GLOAD_LDS16(Bt + (size_t)(n0 + r) * K + kt + c8, Bs + (size_t)(j * 256 + wv * 64) * 8);
    }
    __syncthreads();
#pragma unroll
    for (int ks = 0; ks < 2; ++ks) {
      bf16x8 a[4], bb[4];
#pragma unroll
      for (int mf = 0; mf < 4; ++mf)
        a[mf] = ld_bf8(As + (wr * 64 + mf * 16 + lr) * 64 + ks * 32 + lk * 8);
#pragma unroll
      for (int nf = 0; nf < 4; ++nf)
        bb[nf] = ld_bf8(Bs + (wc * 64 + nf * 16 + lr) * 64 + ks * 32 + lk * 8);
#pragma unroll
      for (int mf = 0; mf < 4; ++mf)
#pragma unroll
        for (int nf = 0; nf < 4; ++nf)
          acc[mf][nf] = __builtin_amdgcn_mfma_f32_16x16x32_bf16(a[mf], bb[nf], acc[mf][nf], 0, 0, 0);
    }
    __syncthreads();
  }
#pragma unroll
  for (int mf = 0; mf < 4; ++mf) {
    int rbase = m0 + wr * 64 + mf * 16 + lk * 4;
    if constexpr (EPI == 3) {
#pragma unroll
      for (int nf = 0; nf < 4; nf += 2) {
        int colv = n0 + wc * 64 + nf * 16 + lr;
        int i = ((colv >> 5) << 4) | (colv & 15);
#pragma unroll
        for (int jj = 0; jj < 4; ++jj) {
          int row = rbase + jj;
          float val = acc[mf][nf][jj], gate = acc[mf][nf + 1][jj];
          float sil = gate / (1.f + __expf(-gate));
          out[(size_t)row * 1024 + i] = f2bf(sil * val);
        }
      }
    } else if constexpr (EPI == 4 || EPI == 5) {
      // token row -> (bimg, hy, wx, iy, ix); rows rbase..rbase+3 share all but ix (contiguous)
      int widx = rbase >> 8, iy = (rbase >> 4) & 15, ix0 = rbase & 15;
      int bimg = widx >> 4, hy = (widx >> 2) & 3, wx = widx & 3;
#pragma unroll
      for (int nf = 0; nf < 4; ++nf) {
        int col = n0 + wc * 64 + nf * 16 + lr;
        size_t obase = (((size_t)(bimg * 512 + col) * 64) + hy * 16 + iy) * 64 + wx * 16 + ix0;
        const float* xp = xg + obase;
        if constexpr (EPI == 4) {
          float* op = outf + obase;
#pragma unroll
          for (int jj = 0; jj < 4; ++jj)
            op[jj] = acc[mf][nf][jj] + bf2f(res[(size_t)(rbase + jj) * 512 + col]) + xp[jj];
        } else {
#pragma unroll
          for (int jj = 0; jj < 4; ++jj)
            out[(size_t)(rbase + jj) * 512 + col] = f2bf(acc[mf][nf][jj] + xp[jj]);
        }
      }
    } else {
#pragma unroll
      for (int nf = 0; nf < 4; ++nf) {
        int col = n0 + wc * 64 + nf * 16 + lr;
#pragma unroll
        for (int jj = 0; jj < 4; ++jj)
          out[(size_t)(rbase + jj) * N + col] = f2bf(acc[mf][nf][jj]);
      }
    }
  }
}

// ---------------- windowed flash attention (R8 proven), qkv natural layout [tok][1536] ----------------
__global__ __launch_bounds__(256, 4) void attn_kernel(
    const u16* __restrict__ qkv, const float* __restrict__ tab2, u16* __restrict__ ob) {
  __shared__ u16 vt[32 * 72];
  __shared__ float tabh4[31 * 32 * 4];
  __shared__ u16 pl[4][16 * 76];
  const int h = blockIdx.x, w = blockIdx.y;
  const int t = threadIdx.x, l = t & 63, wid = t >> 6;
  const u16* qg = qkv + (size_t)(w * 256) * 1536 + h * 32;
  const u16* kg = qg + 512;
  const u16* vg = qg + 1024;
  const float* th = tab2 + h * 961;
  for (int i = t; i < 992; i += 256) {
    int dy = i >> 5, dx = i & 31;
#pragma unroll
    for (int r = 0; r < 4; ++r) {
      int dxr = dx + r;
      tabh4[i * 4 + r] = (dxr <= 30) ? th[dy * 31 + dxr] : 0.f;
    }
  }
  const int q4 = l >> 4, c0 = l & 15;
  const int dx0 = q4 * 4 - c0 + 15;
  bf16x8 qa[4];
#pragma unroll
  for (int mf = 0; mf < 4; ++mf)
    qa[mf] = ld_bf8(qg + (size_t)(wid * 64 + mf * 16 + c0) * 1536 + q4 * 8);
  f32x4 oacc[4][2] = {};
  float psum[4][4] = {};
  for (int ct = 0; ct < 4; ++ct) {
    {
      int r = t & 63, j = t >> 6;
      u16x8 dv = *(const u16x8*)(vg + (size_t)(ct * 64 + r) * 1536 + j * 8);
#pragma unroll
      for (int e = 0; e < 8; ++e) vt[(j * 8 + e) * 72 + r] = dv[e];
    }
    __syncthreads();
    bf16x8 bfr[4];
#pragma unroll
    for (int nf = 0; nf < 4; ++nf)
      bfr[nf] = ld_bf8(kg + (size_t)(ct * 64 + nf * 16 + c0) * 1536 + q4 * 8);
    bf16x8 vfr[2][2];
#pragma unroll
    for (int df = 0; df < 2; ++df)
#pragma unroll
      for (int ks2 = 0; ks2 < 2; ++ks2)
        vfr[df][ks2] = ld_bf8(vt + (df * 16 + c0) * 72 + ks2 * 32 + q4 * 8);
#pragma unroll
    for (int mf = 0; mf < 4; ++mf) {
      const int dyb = wid * 4 + mf - ct * 4 + 15;
      f32x4 sacc[4];
#pragma unroll
      for (int nf = 0; nf < 4; ++nf)
        sacc[nf] = *(const f32x4*)&tabh4[((dyb - nf) * 32 + dx0) * 4];
      __builtin_amdgcn_s_setprio(1);
#pragma unroll
      for (int nf = 0; nf < 4; ++nf)
        sacc[nf] = __builtin_amdgcn_mfma_f32_16x16x32_bf16(qa[mf], bfr[nf], sacc[nf], 0, 0, 0);
      __builtin_amdgcn_s_setprio(0);
#pragma unroll
      for (int nf = 0; nf < 4; ++nf) {
#pragma unroll
        for (int jj = 0; jj < 4; ++jj) {
          float p = EXP2(sacc[nf][jj]);
          psum[mf][jj] += p;
          pl[wid][(q4 * 4 + jj) * 76 + nf * 16 + c0] = cvt_bf(p);
        }
      }
      __builtin_amdgcn_s_setprio(1);
#pragma unroll
      for (int ks2 = 0; ks2 < 2; ++ks2) {
        bf16x8 pa = ld_bf8(&pl[wid][c0 * 76 + ks2 * 32 + q4 * 8]);
        oacc[mf][0] = __builtin_amdgcn_mfma_f32_16x16x32_bf16(pa, vfr[0][ks2], oacc[mf][0], 0, 0, 0);
        oacc[mf][1] = __builtin_amdgcn_mfma_f32_16x16x32_bf16(pa, vfr[1][ks2], oacc[mf][1], 0, 0, 0);
      }
      __builtin_amdgcn_s_setprio(0);
    }
    __syncthreads();
  }
#pragma unroll
  for (int mf = 0; mf < 4; ++mf) {
#pragma unroll
    for (int jj = 0; jj < 4; ++jj) {
      float s = psum[mf][jj];
      s += __shfl_xor(s, 1);
      s += __shfl_xor(s, 2);
      s += __shfl_xor(s, 4);
      s += __shfl_xor(s, 8);
      float inv = 1.f / s;
      int row = wid * 64 + mf * 16 + q4 * 4 + jj;
      size_t obase = ((size_t)w * 256 + row) * 512 + h * 32;
      ob[obase + c0] = f2bf(oacc[mf][0][jj] * inv);
      ob[obase + 16 + c0] = f2bf(oacc[mf][1][jj] * inv);
    }
  }
}

// ---------------- LN2 ----------------
__global__ __launch_bounds__(256, 4) void ln2_kernel(const u16* __restrict__ r1,
    const float* __restrict__ w, const float* __restrict__ b, u16* __restrict__ h2) {
  int t = threadIdx.x, l = t & 63, wid = t >> 6;
  size_t token = (size_t)blockIdx.x * 4 + wid;
  const u16* rp = r1 + token * 512 + l * 8;
  u16x8 raw = *(const u16x8*)rp;
  float v[8]; float s = 0.f, s2 = 0.f;
#pragma unroll
  for (int i = 0; i < 8; ++i) { v[i] = bf2f(raw[i]); s += v[i]; s2 += v[i] * v[i]; }
#pragma unroll
  for (int m = 1; m < 64; m <<= 1) { s += __shfl_xor(s, m); s2 += __shfl_xor(s2, m); }
  float mu = s * (1.f / 512.f);
  float var = s2 * (1.f / 512.f) - mu * mu;
  float rs = rsqrtf(var + 1e-5f);
  u16x8 o;
#pragma unroll
  for (int i = 0; i < 8; ++i) {
    int c = l * 8 + i;
    o[i] = f2bf((v[i] - mu) * rs * w[c] + b[c]);
  }
  *(u16x8*)(h2 + token * 512 + l * 8) = o;
}

extern "C" void kernel_launch(void* const* d_in, const int* in_sizes, int n_in,
                              void* d_out, int out_size, void* d_ws, size_t ws_size,
                              hipStream_t stream) {
  (void)in_sizes; (void)n_in; (void)out_size; (void)ws_size;
  const float* x = (const float*)d_in[0];
  const float* rel_table = (const float*)d_in[1];
  const float* n1w = (const float*)d_in[2];
  const float* n1b = (const float*)d_in[3];
  const float* n2w = (const float*)d_in[4];
  const float* n2b = (const float*)d_in[5];
  const float* qkv_w = (const float*)d_in[6];
  const float* proj_w = (const float*)d_in[7];
  const float* cpb_w1 = (const float*)d_in[8];
  const float* cpb_b1 = (const float*)d_in[9];
  const float* cpb_w2 = (const float*)d_in[10];
  const float* fc1_w = (const float*)d_in[11];
  const float* fc2_w = (const float*)d_in[12];
  float* outp = (float*)d_out;
  char* ws = (char*)d_ws;

  u16* wq = (u16*)(ws + 0);              // 1536x512 bf16 (q cols pre-scaled)
  u16* wp = (u16*)(ws + 1572864);        // 512x512
  u16* w1 = (u16*)(ws + 2097152);        // 2048x512 (permuted)
  u16* w2 = (u16*)(ws + 4194304);        // 512x1024
  float* tab2 = (float*)(ws + 5242880);  // 16x961 f32 (pre-shifted)
  const size_t RB = 67108864;
  u16* R1 = (u16*)(ws + 8388608 + RB);       // r1
  u16* R2 = (u16*)(ws + 8388608 + 2 * RB);   // hbuf -> obuf
  u16* R3 = (u16*)(ws + 8388608 + 3 * RB);   // qkv (201MB, spans R3..R5) -> h2
  u16* R4 = (u16*)(ws + 8388608 + 4 * RB);   // gbuf (134MB, spans R4+R5)

  wtrans_qkv_kernel<<<3072, 256, 0, stream>>>(qkv_w, wq);
  wtrans_kernel<<<1024, 256, 0, stream>>>(proj_w, wp, 512, 512);
  wtrans_fc1_kernel<<<4096, 256, 0, stream>>>(fc1_w, w1);
  wtrans_kernel<<<2048, 256, 0, stream>>>(fc2_w, w2, 1024, 512);
  cpb_kernel<<<961, 256, 0, stream>>>(rel_table, cpb_w1, cpb_b1, cpb_w2, tab2);
  ln1_kernel<<<2048, 256, 0, stream>>>(x, n1w, n1b, R2);
  gemm_bt<0><<<6144, 256, 0, stream>>>(R2, wq, R3, nullptr,
                                       nullptr, nullptr, 65536, 1536, 512);
  attn_kernel<<<dim3(16, 256), 256, 0, stream>>>(R3, tab2, R2);
  gemm_bt<5><<<2048, 256, 0, stream>>>(R2, wp, R1, nullptr,
                                       x, nullptr, 65536, 512, 512);
  ln2_kernel<<<16384, 256, 0, stream>>>(R1, n2w, n2b, R3);
  gemm_bt<3><<<8192, 256, 0, stream>>>(R3, w1, R4, nullptr,
                                       nullptr, nullptr, 65536, 2048, 512);
  gemm_bt<4><<<2048, 256, 0, stream>>>(R4, w2, nullptr, R1,
                                       x, outp, 65536, 512, 1024);
}